// Round 14
// baseline (602.024 us; speedup 1.0000x reference)
//
#include <hip/hip_runtime.h>
#include <hip/hip_fp16.h>

#define N_G   15135
#define E_N   242160
#define BSZ   8
#define K_TOP 7568
#define NH    128
#define NBIN  65536
#define SUFS  65600

typedef float f4v __attribute__((ext_vector_type(4)));
typedef unsigned int u2v __attribute__((ext_vector_type(2)));

// ---------------- utility ----------------
__global__ void zero_kernel(int* __restrict__ p, int n) {
  int i = blockIdx.x * 1024 + threadIdx.x;
  if (i < n) p[i] = 0;
}

__global__ void count_kernel(const int* __restrict__ ei, int* __restrict__ cnt) {
  int e = blockIdx.x * 256 + threadIdx.x;
  if (e < E_N) atomicAdd(&cnt[ei[E_N + e]], 1);
}

// local scan + atomic ticket; emits dinv, packed row descriptor (rowstart,cnt,dinv), scal.
__global__ __launch_bounds__(1024) void scan_kernel(const int* __restrict__ cnt,
                                                    int* __restrict__ rowstart,
                                                    float* __restrict__ dinv,
                                                    int4* __restrict__ rowdesc,
                                                    int* __restrict__ gctr,
                                                    const float* __restrict__ topk_w,
                                                    float* __restrict__ scal) {
  __shared__ int buf[1024];
  __shared__ int base;
  int tid = threadIdx.x;
  int i = blockIdx.x * 1024 + tid;
  int v = (i < N_G) ? cnt[i] : 0;
  float di = 1.0f / sqrtf((float)(v + 1));
  if (i < N_G) dinv[i] = di;
  buf[tid] = v;
  __syncthreads();
  for (int s = 1; s < 1024; s <<= 1) {
    int t = (tid >= s) ? buf[tid - s] : 0;
    __syncthreads();
    buf[tid] += t;
    __syncthreads();
  }
  if (tid == 1023) base = atomicAdd(gctr, buf[1023]);
  __syncthreads();
  if (i < N_G) {
    int rs = base + buf[tid] - v;
    rowstart[i] = rs;
    rowdesc[i] = make_int4(rs, v, __float_as_int(di), 0);
  }
  if (blockIdx.x == 0) {
    __shared__ float fbuf[512];
    if (tid < 512) {
      float w = (tid < 384) ? topk_w[tid] : 0.f;
      fbuf[tid] = w * w;
    }
    __syncthreads();
    for (int s = 256; s > 0; s >>= 1) {
      if (tid < s) fbuf[tid] += fbuf[tid + s];
      __syncthreads();
    }
    if (tid == 0) scal[0] = 1.0f / sqrtf(fbuf[0]);
  }
}

// csr packs (src, dinv[src]).
__global__ void fill_kernel(const int* __restrict__ ei, const int* __restrict__ rowstart,
                            const float* __restrict__ dinv, int* __restrict__ fillc,
                            int2* __restrict__ csr) {
  int e = blockIdx.x * 256 + threadIdx.x;
  if (e < E_N) {
    int s = ei[e], d = ei[E_N + e];
    int pos = rowstart[d] + atomicAdd(&fillc[d], 1);
    csr[pos] = make_int2(s, __float_as_int(dinv[s]));
  }
}

// ---------------- dense matmul, batch-pinned blocks ----------------
// H16: store output rows as fp16 (layer-3: halves gather lines for the score agg).
template<int CIN, bool BR, bool H16>
__global__ __launch_bounds__(256, 6) void mm_kernel(const float* __restrict__ A,
                                                    const float* __restrict__ W,
                                                    const float* __restrict__ bias,
                                                    void* __restrict__ outv) {
  __shared__ float Bst[32][132];
  __shared__ float Ast2[32][68];
  int tid = threadIdx.x;
  int b = blockIdx.x & 7;
  int ib = blockIdx.x >> 3;
  int rb0 = b * N_G + ib * 64;
  int rmax = N_G - ib * 64;
  int c0 = (tid & 31) * 4;
  int r0 = (tid >> 5) * 8;
  float acc[8][4];
#pragma unroll
  for (int i = 0; i < 8; i++)
#pragma unroll
    for (int j = 0; j < 4; j++) acc[i][j] = 0.f;

  for (int k0 = 0; k0 < CIN; k0 += 32) {
    {
      int koff = (tid & 7) * 4;
      int row = tid >> 3;
#pragma unroll
      for (int p = 0; p < 2; ++p) {
        int r = row + p * 32;
        f4v v = {0.f, 0.f, 0.f, 0.f};
        if (r < rmax) v = __builtin_nontemporal_load((const f4v*)(A + (size_t)(rb0 + r) * CIN + k0 + koff));
        Ast2[koff + 0][r] = v.x; Ast2[koff + 1][r] = v.y;
        Ast2[koff + 2][r] = v.z; Ast2[koff + 3][r] = v.w;
      }
    }
    {
      int cc = (tid & 31) * 4;
      int kr = tid >> 5;
#pragma unroll
      for (int p = 0; p < 4; ++p) {
        int k = kr + p * 8;
        *(float4*)&Bst[k][cc] = *(const float4*)(W + (size_t)(k0 + k) * NH + cc);
      }
    }
    __syncthreads();
#pragma unroll 4
    for (int kk = 0; kk < 32; ++kk) {
      float a[8], bb[4];
      *(float4*)&a[0] = *(const float4*)&Ast2[kk][r0];
      *(float4*)&a[4] = *(const float4*)&Ast2[kk][r0 + 4];
      *(float4*)&bb[0] = *(const float4*)&Bst[kk][c0];
#pragma unroll
      for (int i = 0; i < 8; i++)
#pragma unroll
        for (int j = 0; j < 4; j++)
          acc[i][j] = fmaf(a[i], bb[j], acc[i][j]);
    }
    __syncthreads();
  }
  float b0 = 0.f, b1 = 0.f, b2 = 0.f, b3 = 0.f;
  if (BR) { b0 = bias[c0]; b1 = bias[c0+1]; b2 = bias[c0+2]; b3 = bias[c0+3]; }
#pragma unroll
  for (int i = 0; i < 8; i++) {
    int r = r0 + i;
    if (r < rmax) {
      if (H16) {
        __half2 pr[2];
        pr[0] = __floats2half2_rn(acc[i][0], acc[i][1]);
        pr[1] = __floats2half2_rn(acc[i][2], acc[i][3]);
        *(uint2*)((__half*)outv + (size_t)(rb0 + r) * NH + c0) = *(uint2*)pr;
      } else {
        float4 v;
        if (BR) {
          v.x = fmaxf(acc[i][0] + b0, 0.f); v.y = fmaxf(acc[i][1] + b1, 0.f);
          v.z = fmaxf(acc[i][2] + b2, 0.f); v.w = fmaxf(acc[i][3] + b3, 0.f);
        } else {
          v.x = acc[i][0]; v.y = acc[i][1]; v.z = acc[i][2]; v.w = acc[i][3];
        }
        *(float4*)((float*)outv + (size_t)(rb0 + r) * NH + c0) = v;
      }
    }
  }
}

// ---------------- layer-1 x-aggregation: TWO rows per wave, interleaved --------------
__global__ __launch_bounds__(256) void agg64x2_kernel(const float* __restrict__ src,
                                                      const int2* __restrict__ csr,
                                                      const int4* __restrict__ rowdesc,
                                                      float* __restrict__ dst) {
  int b = blockIdx.x & 7;
  int chunk = blockIdx.x >> 3;
  int wave = threadIdx.x >> 6, lane = threadIdx.x & 63;
  int d0 = chunk * 8 + wave * 2;
  if (d0 >= N_G) return;
  d0 = __builtin_amdgcn_readfirstlane(d0);
  int d1 = d0 + 1;
  int has1 = (d1 < N_G);
  int dB = has1 ? d1 : d0;
  int4 rdA = rowdesc[d0];
  int4 rdB = rowdesc[dB];
  int nA = rdA.y, nB = has1 ? rdB.y : 0;
  float dvA = __int_as_float(rdA.z);
  float dvB = __int_as_float(rdB.z);
  const float* sb = src + (size_t)b * N_G * 64;
  const int2* ceA = csr + rdA.x;
  const int2* ceB = csr + rdB.x;
  float selfA = sb[(size_t)d0 * 64 + lane];
  float selfB = sb[(size_t)dB * 64 + lane];
  float axA[4], axB[4];
  axA[0] = dvA * selfA;
  axB[0] = has1 ? dvB * selfB : 0.f;
#pragma unroll
  for (int k = 1; k < 4; ++k) { axA[k] = 0.f; axB[k] = 0.f; }
  int lA = 0, lB = 0;
  while (lA + 8 <= nA && lB + 8 <= nB) {
    int2 pA[8], pB[8]; float vA[8], vB[8];
#pragma unroll
    for (int k = 0; k < 8; ++k) pA[k] = ceA[lA + k];
#pragma unroll
    for (int k = 0; k < 8; ++k) pB[k] = ceB[lB + k];
#pragma unroll
    for (int k = 0; k < 8; ++k) vA[k] = sb[(size_t)pA[k].x * 64 + lane];
#pragma unroll
    for (int k = 0; k < 8; ++k) vB[k] = sb[(size_t)pB[k].x * 64 + lane];
#pragma unroll
    for (int k = 0; k < 8; ++k) axA[k & 3] = fmaf(__int_as_float(pA[k].y), vA[k], axA[k & 3]);
#pragma unroll
    for (int k = 0; k < 8; ++k) axB[k & 3] = fmaf(__int_as_float(pB[k].y), vB[k], axB[k & 3]);
    lA += 8; lB += 8;
  }
  for (; lA + 8 <= nA; lA += 8) {
    int2 pA[8]; float vA[8];
#pragma unroll
    for (int k = 0; k < 8; ++k) pA[k] = ceA[lA + k];
#pragma unroll
    for (int k = 0; k < 8; ++k) vA[k] = sb[(size_t)pA[k].x * 64 + lane];
#pragma unroll
    for (int k = 0; k < 8; ++k) axA[k & 3] = fmaf(__int_as_float(pA[k].y), vA[k], axA[k & 3]);
  }
  for (; lB + 8 <= nB; lB += 8) {
    int2 pB[8]; float vB[8];
#pragma unroll
    for (int k = 0; k < 8; ++k) pB[k] = ceB[lB + k];
#pragma unroll
    for (int k = 0; k < 8; ++k) vB[k] = sb[(size_t)pB[k].x * 64 + lane];
#pragma unroll
    for (int k = 0; k < 8; ++k) axB[k & 3] = fmaf(__int_as_float(pB[k].y), vB[k], axB[k & 3]);
  }
  for (; lA < nA; ++lA) {
    int2 p = ceA[lA];
    axA[0] = fmaf(__int_as_float(p.y), sb[(size_t)p.x * 64 + lane], axA[0]);
  }
  for (; lB < nB; ++lB) {
    int2 p = ceB[lB];
    axB[0] = fmaf(__int_as_float(p.y), sb[(size_t)p.x * 64 + lane], axB[0]);
  }
  {
    float s = (axA[0] + axA[1]) + (axA[2] + axA[3]);
    __builtin_nontemporal_store(dvA * s, &dst[((size_t)b * N_G + d0) * 64 + lane]);
  }
  if (has1) {
    float s = (axB[0] + axB[1]) + (axB[2] + axB[3]);
    __builtin_nontemporal_store(dvB * s, &dst[((size_t)b * N_G + d1) * 64 + lane]);
  }
}

// ---------------- layer-2: 128-ch fp32 aggregation, 2 edges per gather ---------------
__global__ __launch_bounds__(256) void agg128_f4_kernel(const float* __restrict__ hw,
                                                        const int2* __restrict__ csr,
                                                        const int4* __restrict__ rowdesc,
                                                        const float* __restrict__ bias,
                                                        float* __restrict__ hout) {
  int b = blockIdx.x & 7;
  int chunk = blockIdx.x >> 3;
  int wave = threadIdx.x >> 6, lane = threadIdx.x & 63;
  int d0 = chunk * 8 + wave * 2;
  if (d0 >= N_G) return;
  d0 = __builtin_amdgcn_readfirstlane(d0);
  int d1i = d0 + 1;
  int has1 = (d1i < N_G);
  int dB = has1 ? d1i : d0;
  int half = lane >> 5, li = lane & 31;
  int4 rdA = rowdesc[d0];
  int4 rdB = rowdesc[dB];
  int nA = rdA.y, nB = has1 ? rdB.y : 0;
  float dvA = __int_as_float(rdA.z);
  float dvB = __int_as_float(rdB.z);
  const float* sb = hw + (size_t)b * N_G * NH;
  const int2* ceA = csr + rdA.x;
  const int2* ceB = csr + rdB.x;
  auto sel2 = [&](int a0, int a1) { return half ? a1 : a0; };
  f4v aA0 = {0.f,0.f,0.f,0.f}, aA1 = {0.f,0.f,0.f,0.f};
  f4v aB0 = {0.f,0.f,0.f,0.f}, aB1 = {0.f,0.f,0.f,0.f};
  {
    f4v sv = *(const f4v*)(sb + (size_t)d0 * NH + li * 4);
    float ws = (half == 0) ? dvA : 0.f;
    aA0.x = fmaf(ws, sv.x, aA0.x); aA0.y = fmaf(ws, sv.y, aA0.y);
    aA0.z = fmaf(ws, sv.z, aA0.z); aA0.w = fmaf(ws, sv.w, aA0.w);
    f4v svb = *(const f4v*)(sb + (size_t)dB * NH + li * 4);
    float wsb = (half == 0 && has1) ? dvB : 0.f;
    aB0.x = fmaf(wsb, svb.x, aB0.x); aB0.y = fmaf(wsb, svb.y, aB0.y);
    aB0.z = fmaf(wsb, svb.z, aB0.z); aB0.w = fmaf(wsb, svb.w, aB0.w);
  }
  auto batch8 = [&](const int2* ce, int l, f4v& c0, f4v& c1) {
    int2 p[8];
#pragma unroll
    for (int k = 0; k < 8; ++k) p[k] = ce[l + k];
    int s0 = sel2(p[0].x, p[1].x), s1 = sel2(p[2].x, p[3].x);
    int s2 = sel2(p[4].x, p[5].x), s3 = sel2(p[6].x, p[7].x);
    float w0 = __int_as_float(sel2(p[0].y, p[1].y));
    float w1 = __int_as_float(sel2(p[2].y, p[3].y));
    float w2 = __int_as_float(sel2(p[4].y, p[5].y));
    float w3 = __int_as_float(sel2(p[6].y, p[7].y));
    f4v v0 = *(const f4v*)(sb + (size_t)s0 * NH + li * 4);
    f4v v1 = *(const f4v*)(sb + (size_t)s1 * NH + li * 4);
    f4v v2 = *(const f4v*)(sb + (size_t)s2 * NH + li * 4);
    f4v v3 = *(const f4v*)(sb + (size_t)s3 * NH + li * 4);
    c0.x = fmaf(w0, v0.x, c0.x); c0.y = fmaf(w0, v0.y, c0.y);
    c0.z = fmaf(w0, v0.z, c0.z); c0.w = fmaf(w0, v0.w, c0.w);
    c1.x = fmaf(w1, v1.x, c1.x); c1.y = fmaf(w1, v1.y, c1.y);
    c1.z = fmaf(w1, v1.z, c1.z); c1.w = fmaf(w1, v1.w, c1.w);
    c0.x = fmaf(w2, v2.x, c0.x); c0.y = fmaf(w2, v2.y, c0.y);
    c0.z = fmaf(w2, v2.z, c0.z); c0.w = fmaf(w2, v2.w, c0.w);
    c1.x = fmaf(w3, v3.x, c1.x); c1.y = fmaf(w3, v3.y, c1.y);
    c1.z = fmaf(w3, v3.z, c1.z); c1.w = fmaf(w3, v3.w, c1.w);
  };
  int lA = 0, lB = 0;
  while (lA + 8 <= nA && lB + 8 <= nB) {
    batch8(ceA, lA, aA0, aA1);
    batch8(ceB, lB, aB0, aB1);
    lA += 8; lB += 8;
  }
  for (; lA + 8 <= nA; lA += 8) batch8(ceA, lA, aA0, aA1);
  for (; lB + 8 <= nB; lB += 8) batch8(ceB, lB, aB0, aB1);
  while (lA < nA || lB < nB) {
    int hasA = (lA < nA), hasB = (lB < nB);
    int sA = hasA ? ceA[lA].x : d0;
    int wAi = hasA ? ceA[lA].y : 0;
    int sB = hasB ? ceB[lB].x : d0;
    int wBi = hasB ? ceB[lB].y : 0;
    int s = half ? sB : sA;
    float wa = (half == 0 && hasA) ? __int_as_float(wAi) : 0.f;
    float wb = (half == 1 && hasB) ? __int_as_float(wBi) : 0.f;
    f4v v = *(const f4v*)(sb + (size_t)s * NH + li * 4);
    aA0.x = fmaf(wa, v.x, aA0.x); aA0.y = fmaf(wa, v.y, aA0.y);
    aA0.z = fmaf(wa, v.z, aA0.z); aA0.w = fmaf(wa, v.w, aA0.w);
    aB0.x = fmaf(wb, v.x, aB0.x); aB0.y = fmaf(wb, v.y, aB0.y);
    aB0.z = fmaf(wb, v.z, aB0.z); aB0.w = fmaf(wb, v.w, aB0.w);
    lA += hasA; lB += hasB;
  }
  f4v aA, aB;
  aA.x = aA0.x + aA1.x; aA.y = aA0.y + aA1.y;
  aA.z = aA0.z + aA1.z; aA.w = aA0.w + aA1.w;
  aB.x = aB0.x + aB1.x; aB.y = aB0.y + aB1.y;
  aB.z = aB0.z + aB1.z; aB.w = aB0.w + aB1.w;
  aA.x += __shfl_xor(aA.x, 32); aA.y += __shfl_xor(aA.y, 32);
  aA.z += __shfl_xor(aA.z, 32); aA.w += __shfl_xor(aA.w, 32);
  aB.x += __shfl_xor(aB.x, 32); aB.y += __shfl_xor(aB.y, 32);
  aB.z += __shfl_xor(aB.z, 32); aB.w += __shfl_xor(aB.w, 32);

  f4v bb = *(const f4v*)(bias + li * 4);
  float dv = half ? dvB : dvA;
  f4v av;
  av.x = half ? aB.x : aA.x; av.y = half ? aB.y : aA.y;
  av.z = half ? aB.z : aA.z; av.w = half ? aB.w : aA.w;
  f4v r;
  r.x = fmaxf(fmaf(dv, av.x, bb.x), 0.f);
  r.y = fmaxf(fmaf(dv, av.y, bb.y), 0.f);
  r.z = fmaxf(fmaf(dv, av.z, bb.z), 0.f);
  r.w = fmaxf(fmaf(dv, av.w, bb.w), 0.f);
  int dsel = half ? dB : d0;
  if (half == 0 || has1)
    __builtin_nontemporal_store(r, (f4v*)(hout + ((size_t)b * N_G + dsel) * NH + li * 4));
}

// ---------------- layer-3: fp16 table, fused dual-row batch16, v_fma_mix -------------
// 16 gathers (8 per row) issued before any FMA; non-volatile asm lets the scheduler
// overlap next iteration's loads with this iteration's FMAs.
__global__ __launch_bounds__(256) void agg128h2_score_kernel(
    const __half* __restrict__ hwh,
    const int2* __restrict__ csr,
    const int4* __restrict__ rowdesc,
    const float* __restrict__ bias,
    const float* __restrict__ h1,
    const float* __restrict__ h2,
    const float* __restrict__ topk_w,
    const float* __restrict__ fcW,
    const float* __restrict__ scal,
    float* __restrict__ score,
    float* __restrict__ d2a,
    unsigned* __restrict__ keys,
    int* __restrict__ hist) {
  int b = blockIdx.x & 7;
  int chunk = blockIdx.x >> 3;
  int wave = threadIdx.x >> 6, lane = threadIdx.x & 63;
  int d0 = chunk * 8 + wave * 2;
  if (d0 >= N_G) return;
  d0 = __builtin_amdgcn_readfirstlane(d0);
  int d1i = d0 + 1;
  int has1 = (d1i < N_G);
  int dB = has1 ? d1i : d0;
  int half = lane >> 5, li = lane & 31;
  int4 rdA = rowdesc[d0];
  int4 rdB = rowdesc[dB];
  int nA = rdA.y, nB = has1 ? rdB.y : 0;
  float dvA = __int_as_float(rdA.z);
  float dvB = __int_as_float(rdB.z);
  const __half* sb = hwh + (size_t)b * N_G * NH;
  const int2* ceA = csr + rdA.x;
  const int2* ceB = csr + rdB.x;
  auto sel2 = [&](int a0, int a1) { return half ? a1 : a0; };
  // acc[0..3] <- channels li*4 .. li*4+3 (q0.lo, q0.hi, q1.lo, q1.hi); non-volatile asm
  auto mixacc = [](float* c, u2v q, float w) {
    asm("v_fma_mix_f32 %0, %1, %2, %0 op_sel:[0,0,0] op_sel_hi:[1,0,0]"
        : "+v"(c[0]) : "v"(q.x), "v"(w));
    asm("v_fma_mix_f32 %0, %1, %2, %0 op_sel:[1,0,0] op_sel_hi:[1,0,0]"
        : "+v"(c[1]) : "v"(q.x), "v"(w));
    asm("v_fma_mix_f32 %0, %1, %2, %0 op_sel:[0,0,0] op_sel_hi:[1,0,0]"
        : "+v"(c[2]) : "v"(q.y), "v"(w));
    asm("v_fma_mix_f32 %0, %1, %2, %0 op_sel:[1,0,0] op_sel_hi:[1,0,0]"
        : "+v"(c[3]) : "v"(q.y), "v"(w));
  };
  float A0[4] = {0.f,0.f,0.f,0.f}, A1[4] = {0.f,0.f,0.f,0.f};
  float B0[4] = {0.f,0.f,0.f,0.f}, B1[4] = {0.f,0.f,0.f,0.f};
  {
    u2v sv = *(const u2v*)(sb + (size_t)d0 * NH + li * 4);
    mixacc(A0, sv, (half == 0) ? dvA : 0.f);
    u2v svb = *(const u2v*)(sb + (size_t)dB * NH + li * 4);
    mixacc(B0, svb, (half == 0 && has1) ? dvB : 0.f);
  }
  int lA = 0, lB = 0;
  // fused dual-row batch16: all 16 gathers issued before any FMA
  while (lA + 16 <= nA && lB + 16 <= nB) {
    int2 pA[16], pB[16];
#pragma unroll
    for (int k = 0; k < 16; ++k) pA[k] = ceA[lA + k];
#pragma unroll
    for (int k = 0; k < 16; ++k) pB[k] = ceB[lB + k];
    int sA[8], sB[8]; float wA[8], wB[8];
#pragma unroll
    for (int k = 0; k < 8; ++k) {
      sA[k] = sel2(pA[2*k].x, pA[2*k+1].x);
      wA[k] = __int_as_float(sel2(pA[2*k].y, pA[2*k+1].y));
      sB[k] = sel2(pB[2*k].x, pB[2*k+1].x);
      wB[k] = __int_as_float(sel2(pB[2*k].y, pB[2*k+1].y));
    }
    u2v rA[8], rB[8];
#pragma unroll
    for (int k = 0; k < 8; ++k) rA[k] = *(const u2v*)(sb + (size_t)sA[k] * NH + li * 4);
#pragma unroll
    for (int k = 0; k < 8; ++k) rB[k] = *(const u2v*)(sb + (size_t)sB[k] * NH + li * 4);
#pragma unroll
    for (int k = 0; k < 8; ++k) mixacc((k & 1) ? A1 : A0, rA[k], wA[k]);
#pragma unroll
    for (int k = 0; k < 8; ++k) mixacc((k & 1) ? B1 : B0, rB[k], wB[k]);
    lA += 16; lB += 16;
  }
  // single-side batch8 remnants
  auto batch8 = [&](const int2* ce, int l, float* c0, float* c1) {
    int2 p[8];
#pragma unroll
    for (int k = 0; k < 8; ++k) p[k] = ce[l + k];
    int s0 = sel2(p[0].x, p[1].x), s1 = sel2(p[2].x, p[3].x);
    int s2 = sel2(p[4].x, p[5].x), s3 = sel2(p[6].x, p[7].x);
    float w0 = __int_as_float(sel2(p[0].y, p[1].y));
    float w1 = __int_as_float(sel2(p[2].y, p[3].y));
    float w2 = __int_as_float(sel2(p[4].y, p[5].y));
    float w3 = __int_as_float(sel2(p[6].y, p[7].y));
    u2v r0 = *(const u2v*)(sb + (size_t)s0 * NH + li * 4);
    u2v r1 = *(const u2v*)(sb + (size_t)s1 * NH + li * 4);
    u2v r2 = *(const u2v*)(sb + (size_t)s2 * NH + li * 4);
    u2v r3 = *(const u2v*)(sb + (size_t)s3 * NH + li * 4);
    mixacc(c0, r0, w0);
    mixacc(c1, r1, w1);
    mixacc(c0, r2, w2);
    mixacc(c1, r3, w3);
  };
  for (; lA + 8 <= nA; lA += 8) batch8(ceA, lA, A0, A1);
  for (; lB + 8 <= nB; lB += 8) batch8(ceB, lB, B0, B1);
  while (lA < nA || lB < nB) {
    int hasA = (lA < nA), hasB = (lB < nB);
    int sA = hasA ? ceA[lA].x : d0;
    int wAi = hasA ? ceA[lA].y : 0;
    int sB = hasB ? ceB[lB].x : d0;
    int wBi = hasB ? ceB[lB].y : 0;
    int s = half ? sB : sA;
    float wa = (half == 0 && hasA) ? __int_as_float(wAi) : 0.f;
    float wb = (half == 1 && hasB) ? __int_as_float(wBi) : 0.f;
    u2v v = *(const u2v*)(sb + (size_t)s * NH + li * 4);
    mixacc(A0, v, wa);
    mixacc(B0, v, wb);
    lA += hasA; lB += hasB;
  }
  f4v aA, aB;
  aA.x = A0[0] + A1[0]; aA.y = A0[1] + A1[1];
  aA.z = A0[2] + A1[2]; aA.w = A0[3] + A1[3];
  aB.x = B0[0] + B1[0]; aB.y = B0[1] + B1[1];
  aB.z = B0[2] + B1[2]; aB.w = B0[3] + B1[3];
  aA.x += __shfl_xor(aA.x, 32); aA.y += __shfl_xor(aA.y, 32);
  aA.z += __shfl_xor(aA.z, 32); aA.w += __shfl_xor(aA.w, 32);
  aB.x += __shfl_xor(aB.x, 32); aB.y += __shfl_xor(aB.y, 32);
  aB.z += __shfl_xor(aB.z, 32); aB.w += __shfl_xor(aB.w, 32);

  f4v bb = *(const f4v*)(bias + li * 4);
  float dv = half ? dvB : dvA;
  f4v av;
  av.x = half ? aB.x : aA.x; av.y = half ? aB.y : aA.y;
  av.z = half ? aB.z : aA.z; av.w = half ? aB.w : aA.w;
  f4v r;
  r.x = fmaxf(fmaf(dv, av.x, bb.x), 0.f);
  r.y = fmaxf(fmaf(dv, av.y, bb.y), 0.f);
  r.z = fmaxf(fmaf(dv, av.z, bb.z), 0.f);
  r.w = fmaxf(fmaf(dv, av.w, bb.w), 0.f);
  int dsel = half ? dB : d0;

  // score epilogue
  size_t rb = ((size_t)b * N_G + dsel) * NH + li * 4;
  f4v u1 = __builtin_nontemporal_load((const f4v*)(h1 + rb));
  f4v u2 = __builtin_nontemporal_load((const f4v*)(h2 + rb));
  const float* twp = topk_w + li * 12;
  const float* fwp = fcW + li * 12;
  f4v ta = *(const f4v*)(twp + 0), tb2 = *(const f4v*)(twp + 4), tc = *(const f4v*)(twp + 8);
  f4v fa = *(const f4v*)(fwp + 0), fb = *(const f4v*)(fwp + 4), fc = *(const f4v*)(fwp + 8);
  float d1 = u1.x * ta.x + u2.x * ta.y + r.x * ta.z
           + u1.y * ta.w + u2.y * tb2.x + r.y * tb2.y
           + u1.z * tb2.z + u2.z * tb2.w + r.z * tc.x
           + u1.w * tc.y + u2.w * tc.z + r.w * tc.w;
  float d2 = u1.x * fa.x + u2.x * fa.y + r.x * fa.z
           + u1.y * fa.w + u2.y * fb.x + r.y * fb.y
           + u1.z * fb.z + u2.z * fb.w + r.z * fc.x
           + u1.w * fc.y + u2.w * fc.z + r.w * fc.w;
#pragma unroll
  for (int sh = 16; sh > 0; sh >>= 1) {
    d1 += __shfl_down(d1, sh, 32);
    d2 += __shfl_down(d2, sh, 32);
  }
  if (li == 0 && (half == 0 || has1)) {
    int gw = b * N_G + dsel;
    float scv = tanhf(d1 * scal[0]);
    score[gw] = scv;
    d2a[gw] = d2;
    unsigned u = __float_as_uint(scv);
    unsigned k32 = (u & 0x80000000u) ? ~u : (u | 0x80000000u);
    keys[gw] = k32;
    atomicAdd(&hist[b * NBIN + (int)(k32 >> 16)], 1);
  }
}

// ---------------- per-batch suffix sums over 65536 bins ----------------
__global__ __launch_bounds__(1024) void suffix_kernel(const int* __restrict__ hist,
                                                      int* __restrict__ suf) {
  __shared__ int buf[1024];
  int b = blockIdx.x;
  const int* hb = hist + b * NBIN;
  int* sb = suf + b * SUFS;
  int t = threadIdx.x;
  int base = t * 64;
  int s = 0;
  for (int k = 0; k < 64; ++k) s += hb[base + k];
  buf[t] = s;
  __syncthreads();
  for (int off = 1; off < 1024; off <<= 1) {
    int v = (t + off < 1024) ? buf[t + off] : 0;
    __syncthreads();
    buf[t] += v;
    __syncthreads();
  }
  int acc = buf[t] - s;
  if (t == 0) sb[NBIN] = 0;
  for (int k = 63; k >= 0; --k) {
    acc += hb[base + k];
    sb[base + k] = acc;
  }
}

// ---------------- bucket scatter (consumes hist via atomicSub) ----------------
__global__ void scatter_kernel(const unsigned* __restrict__ keys, int* __restrict__ hist,
                               const int* __restrict__ suf, int2* __restrict__ bucket) {
  int b = blockIdx.y;
  int i = blockIdx.x * 256 + threadIdx.x;
  if (i >= N_G) return;
  unsigned k = keys[b * N_G + i];
  int bin = (int)(k >> 16);
  int old = atomicSub(&hist[b * NBIN + bin], 1);
  int pos = suf[b * SUFS + bin + 1] + old - 1;
  bucket[b * N_G + pos] = make_int2((int)k, i);
}

// ---------------- exact stable-descending rank + z scatter ----------------
__global__ void rank_z_kernel(const unsigned* __restrict__ keys, const int* __restrict__ suf,
                              const int2* __restrict__ bucket, const float* __restrict__ score,
                              const float* __restrict__ d2a, const float* __restrict__ fcb,
                              float* __restrict__ z) {
  int b = blockIdx.y;
  int i = blockIdx.x * 256 + threadIdx.x;
  if (i >= N_G) return;
  int gw = b * N_G + i;
  unsigned k = keys[gw];
  int bin = (int)(k >> 16);
  int lo = suf[b * SUFS + bin + 1];
  int hi = suf[b * SUFS + bin];
  int r = lo;
  const int2* bk = bucket + b * N_G;
  for (int p = lo; p < hi; ++p) {
    int2 e = bk[p];
    unsigned kj = (unsigned)e.x;
    r += (kj > k || (kj == k && e.y < i)) ? 1 : 0;
  }
  if (r < K_TOP) z[b * K_TOP + r] = fmaf(score[gw], d2a[gw], fcb[0]);
}

// ---------------- lin1: all 8 batches per block (W read once) ----------------
__global__ __launch_bounds__(256) void lin1_kernel(const float* __restrict__ z,
                                                   const float* __restrict__ W,
                                                   float* __restrict__ hpre) {
  __shared__ float zb[8][237];
  int rs = blockIdx.x;
  int r0 = rs * 237;
  int rn = K_TOP - r0; if (rn > 237) rn = 237;
  for (int t = threadIdx.x; t < 8 * rn; t += 256) {
    int bb = t / rn, rr = t - bb * rn;
    zb[bb][rr] = z[bb * K_TOP + r0 + rr];
  }
  __syncthreads();
  int c = threadIdx.x;
  float a[8][2];
#pragma unroll
  for (int bb = 0; bb < 8; ++bb) { a[bb][0] = 0.f; a[bb][1] = 0.f; }
  for (int r = 0; r < rn; ++r) {
    const float* wr = W + (size_t)(r0 + r) * 512;
    float w0 = wr[c], w1 = wr[c + 256];
#pragma unroll
    for (int bb = 0; bb < 8; ++bb) {
      float zz = zb[bb][r];
      a[bb][0] = fmaf(zz, w0, a[bb][0]);
      a[bb][1] = fmaf(zz, w1, a[bb][1]);
    }
  }
#pragma unroll
  for (int bb = 0; bb < 8; ++bb) {
    atomicAdd(&hpre[bb * 512 + c], a[bb][0]);
    atomicAdd(&hpre[bb * 512 + c + 256], a[bb][1]);
  }
}

// ---------------- lin2 + log_softmax ----------------
__global__ __launch_bounds__(128) void lin2_kernel(const float* __restrict__ hpre,
                                                   const float* __restrict__ l1b,
                                                   const float* __restrict__ W2,
                                                   const float* __restrict__ l2b,
                                                   float* __restrict__ out) {
  int b = blockIdx.x, tid = threadIdx.x;
  float a0 = 0.f, a1 = 0.f;
  for (int j = tid; j < 512; j += 128) {
    float t = fmaxf(hpre[b * 512 + j] + l1b[j], 0.f);
    a0 = fmaf(t, W2[j * 2 + 0], a0);
    a1 = fmaf(t, W2[j * 2 + 1], a1);
  }
#pragma unroll
  for (int s = 32; s > 0; s >>= 1) {
    a0 += __shfl_down(a0, s);
    a1 += __shfl_down(a1, s);
  }
  __shared__ float red[2][2];
  if ((tid & 63) == 0) { red[tid >> 6][0] = a0; red[tid >> 6][1] = a1; }
  __syncthreads();
  if (tid == 0) {
    float l0 = red[0][0] + red[1][0] + l2b[0];
    float l1 = red[0][1] + red[1][1] + l2b[1];
    float m = fmaxf(l0, l1);
    float lse = m + logf(expf(l0 - m) + expf(l1 - m));
    out[b * 2 + 0] = l0 - lse;
    out[b * 2 + 1] = l1 - lse;
  }
}

extern "C" void kernel_launch(void* const* d_in, const int* in_sizes, int n_in,
                              void* d_out, int out_size, void* d_ws, size_t ws_size,
                              hipStream_t stream) {
  const float* x   = (const float*)d_in[0];
  const int*   ei  = (const int*)d_in[2];
  const float* W1  = (const float*)d_in[3];
  const float* b1  = (const float*)d_in[4];
  const float* W2  = (const float*)d_in[5];
  const float* b2  = (const float*)d_in[6];
  const float* W3  = (const float*)d_in[7];
  const float* b3  = (const float*)d_in[8];
  const float* tkw = (const float*)d_in[9];
  const float* fcW = (const float*)d_in[10];
  const float* fcb = (const float*)d_in[11];
  const float* l1W = (const float*)d_in[12];
  const float* l1b = (const float*)d_in[13];
  const float* l2W = (const float*)d_in[14];
  const float* l2b = (const float*)d_in[15];
  float* out = (float*)d_out;

  char* ws = (char*)d_ws;
  size_t off = 0;
  auto alloc = [&](size_t bytes) {
    char* p = ws + off;
    off += (bytes + 255) & ~(size_t)255;
    return p;
  };
  // zero-init region (contiguous): cnt, fillc, gctr, hpre, hist
  int*   cnt   = (int*)alloc(15136 * 4);
  int*   fillc = (int*)alloc(15136 * 4);
  int*   gctr  = (int*)alloc(256);
  float* hpre  = (float*)alloc(4096 * 4);
  int*   hist  = (int*)alloc((size_t)BSZ * NBIN * 4);
  // --- end zero region ---
  int*   rowstart = (int*)alloc(15136 * 4);
  float* dinv  = (float*)alloc(15136 * 4);
  int4*  rowdesc = (int4*)alloc(15136 * 16);
  float* scal  = (float*)alloc(64);
  float* z     = (float*)alloc((size_t)BSZ * K_TOP * 4);
  float* score = (float*)alloc(121088 * 4);
  float* d2a   = (float*)alloc(121088 * 4);
  unsigned* keys = (unsigned*)alloc(121088 * 4);
  int*   suf   = (int*)alloc((size_t)BSZ * SUFS * 4);
  int2*  bucket = (int2*)alloc(121088 * 8);
  int2*  csr   = (int2*)alloc((size_t)E_N * 8);
  float* ax = (float*)alloc((size_t)BSZ * N_G * 64 * 4);
  float* hw = (float*)alloc((size_t)BSZ * N_G * NH * 4);  // fp32 (layer2) / fp16 (layer3, half used)
  float* h1 = (float*)alloc((size_t)BSZ * N_G * NH * 4);
  float* h2 = (float*)alloc((size_t)BSZ * N_G * NH * 4);
  (void)ws_size; (void)in_sizes; (void)n_in; (void)out_size;

  int zero_n = (int)(((char*)rowstart - (char*)cnt) / 4);
  zero_kernel<<<(zero_n + 1023) / 1024, 1024, 0, stream>>>(cnt, zero_n);
  count_kernel<<<(E_N + 255) / 256, 256, 0, stream>>>(ei, cnt);
  scan_kernel<<<(N_G + 1023) / 1024, 1024, 0, stream>>>(cnt, rowstart, dinv, rowdesc, gctr, tkw, scal);
  fill_kernel<<<(E_N + 255) / 256, 256, 0, stream>>>(ei, rowstart, dinv, fillc, csr);

  dim3 mmg(8 * 237);  // batch-pinned: b = blk&7
  int aggblocks2 = 8 * ((N_G + 7) / 8);   // 2 rows/wave agg kernels

  // layer 1: dual-row 8-deep agg(x) @ W1 (commutation)
  agg64x2_kernel<<<aggblocks2, 256, 0, stream>>>(x, csr, rowdesc, ax);
  mm_kernel<64, true, false><<<mmg, 256, 0, stream>>>(ax, W1, b1, h1);
  // layer 2: fp32 full-width agg, 2 edges/gather, 8 VMEM outstanding
  mm_kernel<128, false, false><<<mmg, 256, 0, stream>>>(h1, W2, nullptr, hw);
  agg128_f4_kernel<<<aggblocks2, 256, 0, stream>>>(hw, csr, rowdesc, b2, h2);
  // layer 3: fp16 table (L2-fit), fused dual-row batch16, fused score
  mm_kernel<128, false, true><<<mmg, 256, 0, stream>>>(h2, W3, nullptr, hw);
  agg128h2_score_kernel<<<aggblocks2, 256, 0, stream>>>((const __half*)hw, csr, rowdesc, b3,
                                                        h1, h2, tkw, fcW, scal,
                                                        score, d2a, keys, hist);

  dim3 ng((N_G + 255) / 256, BSZ);
  suffix_kernel<<<BSZ, 1024, 0, stream>>>(hist, suf);
  scatter_kernel<<<ng, 256, 0, stream>>>(keys, hist, suf, bucket);
  rank_z_kernel<<<ng, 256, 0, stream>>>(keys, suf, bucket, score, d2a, fcb, z);

  lin1_kernel<<<32, 256, 0, stream>>>(z, l1W, hpre);
  lin2_kernel<<<BSZ, 128, 0, stream>>>(hpre, l1b, l2W, l2b, out);
}

// Round 15
// 590.241 us; speedup vs baseline: 1.0200x; 1.0200x over previous
//
#include <hip/hip_runtime.h>
#include <hip/hip_fp16.h>

#define N_G   15135
#define E_N   242160
#define BSZ   8
#define K_TOP 7568
#define NH    128
#define NBIN  65536
#define SUFS  65600

typedef float f4v __attribute__((ext_vector_type(4)));
typedef unsigned int u2v __attribute__((ext_vector_type(2)));

// ---------------- utility ----------------
__global__ void zero_kernel(int* __restrict__ p, int n) {
  int i = blockIdx.x * 1024 + threadIdx.x;
  if (i < n) p[i] = 0;
}

__global__ void count_kernel(const int* __restrict__ ei, int* __restrict__ cnt) {
  int e = blockIdx.x * 256 + threadIdx.x;
  if (e < E_N) atomicAdd(&cnt[ei[E_N + e]], 1);
}

// local scan + atomic ticket; emits dinv, packed row descriptor (rowstart,cnt,dinv), scal.
__global__ __launch_bounds__(1024) void scan_kernel(const int* __restrict__ cnt,
                                                    int* __restrict__ rowstart,
                                                    float* __restrict__ dinv,
                                                    int4* __restrict__ rowdesc,
                                                    int* __restrict__ gctr,
                                                    const float* __restrict__ topk_w,
                                                    float* __restrict__ scal) {
  __shared__ int buf[1024];
  __shared__ int base;
  int tid = threadIdx.x;
  int i = blockIdx.x * 1024 + tid;
  int v = (i < N_G) ? cnt[i] : 0;
  float di = 1.0f / sqrtf((float)(v + 1));
  if (i < N_G) dinv[i] = di;
  buf[tid] = v;
  __syncthreads();
  for (int s = 1; s < 1024; s <<= 1) {
    int t = (tid >= s) ? buf[tid - s] : 0;
    __syncthreads();
    buf[tid] += t;
    __syncthreads();
  }
  if (tid == 1023) base = atomicAdd(gctr, buf[1023]);
  __syncthreads();
  if (i < N_G) {
    int rs = base + buf[tid] - v;
    rowstart[i] = rs;
    rowdesc[i] = make_int4(rs, v, __float_as_int(di), 0);
  }
  if (blockIdx.x == 0) {
    __shared__ float fbuf[512];
    if (tid < 512) {
      float w = (tid < 384) ? topk_w[tid] : 0.f;
      fbuf[tid] = w * w;
    }
    __syncthreads();
    for (int s = 256; s > 0; s >>= 1) {
      if (tid < s) fbuf[tid] += fbuf[tid + s];
      __syncthreads();
    }
    if (tid == 0) scal[0] = 1.0f / sqrtf(fbuf[0]);
  }
}

// csr packs (src, dinv[src]).
__global__ void fill_kernel(const int* __restrict__ ei, const int* __restrict__ rowstart,
                            const float* __restrict__ dinv, int* __restrict__ fillc,
                            int2* __restrict__ csr) {
  int e = blockIdx.x * 256 + threadIdx.x;
  if (e < E_N) {
    int s = ei[e], d = ei[E_N + e];
    int pos = rowstart[d] + atomicAdd(&fillc[d], 1);
    csr[pos] = make_int2(s, __float_as_int(dinv[s]));
  }
}

// ---------------- dense matmul, batch-pinned blocks ----------------
// H16: store output rows as fp16 (layer-3: halves gather lines for the score agg).
template<int CIN, bool BR, bool H16>
__global__ __launch_bounds__(256, 6) void mm_kernel(const float* __restrict__ A,
                                                    const float* __restrict__ W,
                                                    const float* __restrict__ bias,
                                                    void* __restrict__ outv) {
  __shared__ float Bst[32][132];
  __shared__ float Ast2[32][68];
  int tid = threadIdx.x;
  int b = blockIdx.x & 7;
  int ib = blockIdx.x >> 3;
  int rb0 = b * N_G + ib * 64;
  int rmax = N_G - ib * 64;
  int c0 = (tid & 31) * 4;
  int r0 = (tid >> 5) * 8;
  float acc[8][4];
#pragma unroll
  for (int i = 0; i < 8; i++)
#pragma unroll
    for (int j = 0; j < 4; j++) acc[i][j] = 0.f;

  for (int k0 = 0; k0 < CIN; k0 += 32) {
    {
      int koff = (tid & 7) * 4;
      int row = tid >> 3;
#pragma unroll
      for (int p = 0; p < 2; ++p) {
        int r = row + p * 32;
        f4v v = {0.f, 0.f, 0.f, 0.f};
        if (r < rmax) v = __builtin_nontemporal_load((const f4v*)(A + (size_t)(rb0 + r) * CIN + k0 + koff));
        Ast2[koff + 0][r] = v.x; Ast2[koff + 1][r] = v.y;
        Ast2[koff + 2][r] = v.z; Ast2[koff + 3][r] = v.w;
      }
    }
    {
      int cc = (tid & 31) * 4;
      int kr = tid >> 5;
#pragma unroll
      for (int p = 0; p < 4; ++p) {
        int k = kr + p * 8;
        *(float4*)&Bst[k][cc] = *(const float4*)(W + (size_t)(k0 + k) * NH + cc);
      }
    }
    __syncthreads();
#pragma unroll 4
    for (int kk = 0; kk < 32; ++kk) {
      float a[8], bb[4];
      *(float4*)&a[0] = *(const float4*)&Ast2[kk][r0];
      *(float4*)&a[4] = *(const float4*)&Ast2[kk][r0 + 4];
      *(float4*)&bb[0] = *(const float4*)&Bst[kk][c0];
#pragma unroll
      for (int i = 0; i < 8; i++)
#pragma unroll
        for (int j = 0; j < 4; j++)
          acc[i][j] = fmaf(a[i], bb[j], acc[i][j]);
    }
    __syncthreads();
  }
  float b0 = 0.f, b1 = 0.f, b2 = 0.f, b3 = 0.f;
  if (BR) { b0 = bias[c0]; b1 = bias[c0+1]; b2 = bias[c0+2]; b3 = bias[c0+3]; }
#pragma unroll
  for (int i = 0; i < 8; i++) {
    int r = r0 + i;
    if (r < rmax) {
      if (H16) {
        __half2 pr[2];
        pr[0] = __floats2half2_rn(acc[i][0], acc[i][1]);
        pr[1] = __floats2half2_rn(acc[i][2], acc[i][3]);
        *(uint2*)((__half*)outv + (size_t)(rb0 + r) * NH + c0) = *(uint2*)pr;
      } else {
        float4 v;
        if (BR) {
          v.x = fmaxf(acc[i][0] + b0, 0.f); v.y = fmaxf(acc[i][1] + b1, 0.f);
          v.z = fmaxf(acc[i][2] + b2, 0.f); v.w = fmaxf(acc[i][3] + b3, 0.f);
        } else {
          v.x = acc[i][0]; v.y = acc[i][1]; v.z = acc[i][2]; v.w = acc[i][3];
        }
        *(float4*)((float*)outv + (size_t)(rb0 + r) * NH + c0) = v;
      }
    }
  }
}

// ---------------- layer-1 x-aggregation: TWO rows per wave, interleaved --------------
__global__ __launch_bounds__(256) void agg64x2_kernel(const float* __restrict__ src,
                                                      const int2* __restrict__ csr,
                                                      const int4* __restrict__ rowdesc,
                                                      float* __restrict__ dst) {
  int b = blockIdx.x & 7;
  int chunk = blockIdx.x >> 3;
  int wave = threadIdx.x >> 6, lane = threadIdx.x & 63;
  int d0 = chunk * 8 + wave * 2;
  if (d0 >= N_G) return;
  d0 = __builtin_amdgcn_readfirstlane(d0);
  int d1 = d0 + 1;
  int has1 = (d1 < N_G);
  int dB = has1 ? d1 : d0;
  int4 rdA = rowdesc[d0];
  int4 rdB = rowdesc[dB];
  int nA = rdA.y, nB = has1 ? rdB.y : 0;
  float dvA = __int_as_float(rdA.z);
  float dvB = __int_as_float(rdB.z);
  const float* sb = src + (size_t)b * N_G * 64;
  const int2* ceA = csr + rdA.x;
  const int2* ceB = csr + rdB.x;
  float selfA = sb[(size_t)d0 * 64 + lane];
  float selfB = sb[(size_t)dB * 64 + lane];
  float axA[4], axB[4];
  axA[0] = dvA * selfA;
  axB[0] = has1 ? dvB * selfB : 0.f;
#pragma unroll
  for (int k = 1; k < 4; ++k) { axA[k] = 0.f; axB[k] = 0.f; }
  int lA = 0, lB = 0;
  while (lA + 8 <= nA && lB + 8 <= nB) {
    int2 pA[8], pB[8]; float vA[8], vB[8];
#pragma unroll
    for (int k = 0; k < 8; ++k) pA[k] = ceA[lA + k];
#pragma unroll
    for (int k = 0; k < 8; ++k) pB[k] = ceB[lB + k];
#pragma unroll
    for (int k = 0; k < 8; ++k) vA[k] = sb[(size_t)pA[k].x * 64 + lane];
#pragma unroll
    for (int k = 0; k < 8; ++k) vB[k] = sb[(size_t)pB[k].x * 64 + lane];
#pragma unroll
    for (int k = 0; k < 8; ++k) axA[k & 3] = fmaf(__int_as_float(pA[k].y), vA[k], axA[k & 3]);
#pragma unroll
    for (int k = 0; k < 8; ++k) axB[k & 3] = fmaf(__int_as_float(pB[k].y), vB[k], axB[k & 3]);
    lA += 8; lB += 8;
  }
  for (; lA + 8 <= nA; lA += 8) {
    int2 pA[8]; float vA[8];
#pragma unroll
    for (int k = 0; k < 8; ++k) pA[k] = ceA[lA + k];
#pragma unroll
    for (int k = 0; k < 8; ++k) vA[k] = sb[(size_t)pA[k].x * 64 + lane];
#pragma unroll
    for (int k = 0; k < 8; ++k) axA[k & 3] = fmaf(__int_as_float(pA[k].y), vA[k], axA[k & 3]);
  }
  for (; lB + 8 <= nB; lB += 8) {
    int2 pB[8]; float vB[8];
#pragma unroll
    for (int k = 0; k < 8; ++k) pB[k] = ceB[lB + k];
#pragma unroll
    for (int k = 0; k < 8; ++k) vB[k] = sb[(size_t)pB[k].x * 64 + lane];
#pragma unroll
    for (int k = 0; k < 8; ++k) axB[k & 3] = fmaf(__int_as_float(pB[k].y), vB[k], axB[k & 3]);
  }
  for (; lA < nA; ++lA) {
    int2 p = ceA[lA];
    axA[0] = fmaf(__int_as_float(p.y), sb[(size_t)p.x * 64 + lane], axA[0]);
  }
  for (; lB < nB; ++lB) {
    int2 p = ceB[lB];
    axB[0] = fmaf(__int_as_float(p.y), sb[(size_t)p.x * 64 + lane], axB[0]);
  }
  {
    float s = (axA[0] + axA[1]) + (axA[2] + axA[3]);
    __builtin_nontemporal_store(dvA * s, &dst[((size_t)b * N_G + d0) * 64 + lane]);
  }
  if (has1) {
    float s = (axB[0] + axB[1]) + (axB[2] + axB[3]);
    __builtin_nontemporal_store(dvB * s, &dst[((size_t)b * N_G + d1) * 64 + lane]);
  }
}

// ---------------- layer-2: 128-ch fp32 aggregation, 2 edges per gather ---------------
__global__ __launch_bounds__(256) void agg128_f4_kernel(const float* __restrict__ hw,
                                                        const int2* __restrict__ csr,
                                                        const int4* __restrict__ rowdesc,
                                                        const float* __restrict__ bias,
                                                        float* __restrict__ hout) {
  int b = blockIdx.x & 7;
  int chunk = blockIdx.x >> 3;
  int wave = threadIdx.x >> 6, lane = threadIdx.x & 63;
  int d0 = chunk * 8 + wave * 2;
  if (d0 >= N_G) return;
  d0 = __builtin_amdgcn_readfirstlane(d0);
  int d1i = d0 + 1;
  int has1 = (d1i < N_G);
  int dB = has1 ? d1i : d0;
  int half = lane >> 5, li = lane & 31;
  int4 rdA = rowdesc[d0];
  int4 rdB = rowdesc[dB];
  int nA = rdA.y, nB = has1 ? rdB.y : 0;
  float dvA = __int_as_float(rdA.z);
  float dvB = __int_as_float(rdB.z);
  const float* sb = hw + (size_t)b * N_G * NH;
  const int2* ceA = csr + rdA.x;
  const int2* ceB = csr + rdB.x;
  auto sel2 = [&](int a0, int a1) { return half ? a1 : a0; };
  f4v aA0 = {0.f,0.f,0.f,0.f}, aA1 = {0.f,0.f,0.f,0.f};
  f4v aB0 = {0.f,0.f,0.f,0.f}, aB1 = {0.f,0.f,0.f,0.f};
  {
    f4v sv = *(const f4v*)(sb + (size_t)d0 * NH + li * 4);
    float ws = (half == 0) ? dvA : 0.f;
    aA0.x = fmaf(ws, sv.x, aA0.x); aA0.y = fmaf(ws, sv.y, aA0.y);
    aA0.z = fmaf(ws, sv.z, aA0.z); aA0.w = fmaf(ws, sv.w, aA0.w);
    f4v svb = *(const f4v*)(sb + (size_t)dB * NH + li * 4);
    float wsb = (half == 0 && has1) ? dvB : 0.f;
    aB0.x = fmaf(wsb, svb.x, aB0.x); aB0.y = fmaf(wsb, svb.y, aB0.y);
    aB0.z = fmaf(wsb, svb.z, aB0.z); aB0.w = fmaf(wsb, svb.w, aB0.w);
  }
  auto batch8 = [&](const int2* ce, int l, f4v& c0, f4v& c1) {
    int2 p[8];
#pragma unroll
    for (int k = 0; k < 8; ++k) p[k] = ce[l + k];
    int s0 = sel2(p[0].x, p[1].x), s1 = sel2(p[2].x, p[3].x);
    int s2 = sel2(p[4].x, p[5].x), s3 = sel2(p[6].x, p[7].x);
    float w0 = __int_as_float(sel2(p[0].y, p[1].y));
    float w1 = __int_as_float(sel2(p[2].y, p[3].y));
    float w2 = __int_as_float(sel2(p[4].y, p[5].y));
    float w3 = __int_as_float(sel2(p[6].y, p[7].y));
    f4v v0 = *(const f4v*)(sb + (size_t)s0 * NH + li * 4);
    f4v v1 = *(const f4v*)(sb + (size_t)s1 * NH + li * 4);
    f4v v2 = *(const f4v*)(sb + (size_t)s2 * NH + li * 4);
    f4v v3 = *(const f4v*)(sb + (size_t)s3 * NH + li * 4);
    c0.x = fmaf(w0, v0.x, c0.x); c0.y = fmaf(w0, v0.y, c0.y);
    c0.z = fmaf(w0, v0.z, c0.z); c0.w = fmaf(w0, v0.w, c0.w);
    c1.x = fmaf(w1, v1.x, c1.x); c1.y = fmaf(w1, v1.y, c1.y);
    c1.z = fmaf(w1, v1.z, c1.z); c1.w = fmaf(w1, v1.w, c1.w);
    c0.x = fmaf(w2, v2.x, c0.x); c0.y = fmaf(w2, v2.y, c0.y);
    c0.z = fmaf(w2, v2.z, c0.z); c0.w = fmaf(w2, v2.w, c0.w);
    c1.x = fmaf(w3, v3.x, c1.x); c1.y = fmaf(w3, v3.y, c1.y);
    c1.z = fmaf(w3, v3.z, c1.z); c1.w = fmaf(w3, v3.w, c1.w);
  };
  int lA = 0, lB = 0;
  while (lA + 8 <= nA && lB + 8 <= nB) {
    batch8(ceA, lA, aA0, aA1);
    batch8(ceB, lB, aB0, aB1);
    lA += 8; lB += 8;
  }
  for (; lA + 8 <= nA; lA += 8) batch8(ceA, lA, aA0, aA1);
  for (; lB + 8 <= nB; lB += 8) batch8(ceB, lB, aB0, aB1);
  while (lA < nA || lB < nB) {
    int hasA = (lA < nA), hasB = (lB < nB);
    int sA = hasA ? ceA[lA].x : d0;
    int wAi = hasA ? ceA[lA].y : 0;
    int sB = hasB ? ceB[lB].x : d0;
    int wBi = hasB ? ceB[lB].y : 0;
    int s = half ? sB : sA;
    float wa = (half == 0 && hasA) ? __int_as_float(wAi) : 0.f;
    float wb = (half == 1 && hasB) ? __int_as_float(wBi) : 0.f;
    f4v v = *(const f4v*)(sb + (size_t)s * NH + li * 4);
    aA0.x = fmaf(wa, v.x, aA0.x); aA0.y = fmaf(wa, v.y, aA0.y);
    aA0.z = fmaf(wa, v.z, aA0.z); aA0.w = fmaf(wa, v.w, aA0.w);
    aB0.x = fmaf(wb, v.x, aB0.x); aB0.y = fmaf(wb, v.y, aB0.y);
    aB0.z = fmaf(wb, v.z, aB0.z); aB0.w = fmaf(wb, v.w, aB0.w);
    lA += hasA; lB += hasB;
  }
  f4v aA, aB;
  aA.x = aA0.x + aA1.x; aA.y = aA0.y + aA1.y;
  aA.z = aA0.z + aA1.z; aA.w = aA0.w + aA1.w;
  aB.x = aB0.x + aB1.x; aB.y = aB0.y + aB1.y;
  aB.z = aB0.z + aB1.z; aB.w = aB0.w + aB1.w;
  aA.x += __shfl_xor(aA.x, 32); aA.y += __shfl_xor(aA.y, 32);
  aA.z += __shfl_xor(aA.z, 32); aA.w += __shfl_xor(aA.w, 32);
  aB.x += __shfl_xor(aB.x, 32); aB.y += __shfl_xor(aB.y, 32);
  aB.z += __shfl_xor(aB.z, 32); aB.w += __shfl_xor(aB.w, 32);

  f4v bb = *(const f4v*)(bias + li * 4);
  float dv = half ? dvB : dvA;
  f4v av;
  av.x = half ? aB.x : aA.x; av.y = half ? aB.y : aA.y;
  av.z = half ? aB.z : aA.z; av.w = half ? aB.w : aA.w;
  f4v r;
  r.x = fmaxf(fmaf(dv, av.x, bb.x), 0.f);
  r.y = fmaxf(fmaf(dv, av.y, bb.y), 0.f);
  r.z = fmaxf(fmaf(dv, av.z, bb.z), 0.f);
  r.w = fmaxf(fmaf(dv, av.w, bb.w), 0.f);
  int dsel = half ? dB : d0;
  if (half == 0 || has1)
    __builtin_nontemporal_store(r, (f4v*)(hout + ((size_t)b * N_G + dsel) * NH + li * 4));
}

// ---------------- layer-3: fp16 table, dual-row batch8, fused score ------------------
__global__ __launch_bounds__(256) void agg128h2_score_kernel(
    const __half* __restrict__ hwh,
    const int2* __restrict__ csr,
    const int4* __restrict__ rowdesc,
    const float* __restrict__ bias,
    const float* __restrict__ h1,
    const float* __restrict__ h2,
    const float* __restrict__ topk_w,
    const float* __restrict__ fcW,
    const float* __restrict__ scal,
    float* __restrict__ score,
    float* __restrict__ d2a,
    unsigned* __restrict__ keys,
    int* __restrict__ hist) {
  int b = blockIdx.x & 7;
  int chunk = blockIdx.x >> 3;
  int wave = threadIdx.x >> 6, lane = threadIdx.x & 63;
  int d0 = chunk * 8 + wave * 2;
  if (d0 >= N_G) return;
  d0 = __builtin_amdgcn_readfirstlane(d0);
  int d1i = d0 + 1;
  int has1 = (d1i < N_G);
  int dB = has1 ? d1i : d0;
  int half = lane >> 5, li = lane & 31;
  int4 rdA = rowdesc[d0];
  int4 rdB = rowdesc[dB];
  int nA = rdA.y, nB = has1 ? rdB.y : 0;
  float dvA = __int_as_float(rdA.z);
  float dvB = __int_as_float(rdB.z);
  const __half* sb = hwh + (size_t)b * N_G * NH;
  const int2* ceA = csr + rdA.x;
  const int2* ceB = csr + rdB.x;
  auto sel2 = [&](int a0, int a1) { return half ? a1 : a0; };
  auto h2f = [](u2v raw) {
    unsigned q0 = raw.x, q1 = raw.y;
    float2 f0 = __half22float2(*(const __half2*)&q0);
    float2 f1 = __half22float2(*(const __half2*)&q1);
    f4v v; v.x = f0.x; v.y = f0.y; v.z = f1.x; v.w = f1.y;
    return v;
  };
  f4v aA0 = {0.f,0.f,0.f,0.f}, aA1 = {0.f,0.f,0.f,0.f};
  f4v aB0 = {0.f,0.f,0.f,0.f}, aB1 = {0.f,0.f,0.f,0.f};
  {
    f4v sv = h2f(*(const u2v*)(sb + (size_t)d0 * NH + li * 4));
    float ws = (half == 0) ? dvA : 0.f;
    aA0.x = fmaf(ws, sv.x, aA0.x); aA0.y = fmaf(ws, sv.y, aA0.y);
    aA0.z = fmaf(ws, sv.z, aA0.z); aA0.w = fmaf(ws, sv.w, aA0.w);
    f4v svb = h2f(*(const u2v*)(sb + (size_t)dB * NH + li * 4));
    float wsb = (half == 0 && has1) ? dvB : 0.f;
    aB0.x = fmaf(wsb, svb.x, aB0.x); aB0.y = fmaf(wsb, svb.y, aB0.y);
    aB0.z = fmaf(wsb, svb.z, aB0.z); aB0.w = fmaf(wsb, svb.w, aB0.w);
  }
  auto batch8 = [&](const int2* ce, int l, f4v& c0, f4v& c1) {
    int2 p[8];
#pragma unroll
    for (int k = 0; k < 8; ++k) p[k] = ce[l + k];
    int s0 = sel2(p[0].x, p[1].x), s1 = sel2(p[2].x, p[3].x);
    int s2 = sel2(p[4].x, p[5].x), s3 = sel2(p[6].x, p[7].x);
    float w0 = __int_as_float(sel2(p[0].y, p[1].y));
    float w1 = __int_as_float(sel2(p[2].y, p[3].y));
    float w2 = __int_as_float(sel2(p[4].y, p[5].y));
    float w3 = __int_as_float(sel2(p[6].y, p[7].y));
    u2v r0 = *(const u2v*)(sb + (size_t)s0 * NH + li * 4);
    u2v r1 = *(const u2v*)(sb + (size_t)s1 * NH + li * 4);
    u2v r2 = *(const u2v*)(sb + (size_t)s2 * NH + li * 4);
    u2v r3 = *(const u2v*)(sb + (size_t)s3 * NH + li * 4);
    f4v v0 = h2f(r0), v1 = h2f(r1), v2 = h2f(r2), v3 = h2f(r3);
    c0.x = fmaf(w0, v0.x, c0.x); c0.y = fmaf(w0, v0.y, c0.y);
    c0.z = fmaf(w0, v0.z, c0.z); c0.w = fmaf(w0, v0.w, c0.w);
    c1.x = fmaf(w1, v1.x, c1.x); c1.y = fmaf(w1, v1.y, c1.y);
    c1.z = fmaf(w1, v1.z, c1.z); c1.w = fmaf(w1, v1.w, c1.w);
    c0.x = fmaf(w2, v2.x, c0.x); c0.y = fmaf(w2, v2.y, c0.y);
    c0.z = fmaf(w2, v2.z, c0.z); c0.w = fmaf(w2, v2.w, c0.w);
    c1.x = fmaf(w3, v3.x, c1.x); c1.y = fmaf(w3, v3.y, c1.y);
    c1.z = fmaf(w3, v3.z, c1.z); c1.w = fmaf(w3, v3.w, c1.w);
  };
  int lA = 0, lB = 0;
  while (lA + 8 <= nA && lB + 8 <= nB) {
    batch8(ceA, lA, aA0, aA1);
    batch8(ceB, lB, aB0, aB1);
    lA += 8; lB += 8;
  }
  for (; lA + 8 <= nA; lA += 8) batch8(ceA, lA, aA0, aA1);
  for (; lB + 8 <= nB; lB += 8) batch8(ceB, lB, aB0, aB1);
  while (lA < nA || lB < nB) {
    int hasA = (lA < nA), hasB = (lB < nB);
    int sA = hasA ? ceA[lA].x : d0;
    int wAi = hasA ? ceA[lA].y : 0;
    int sB = hasB ? ceB[lB].x : d0;
    int wBi = hasB ? ceB[lB].y : 0;
    int s = half ? sB : sA;
    float wa = (half == 0 && hasA) ? __int_as_float(wAi) : 0.f;
    float wb = (half == 1 && hasB) ? __int_as_float(wBi) : 0.f;
    f4v v = h2f(*(const u2v*)(sb + (size_t)s * NH + li * 4));
    aA0.x = fmaf(wa, v.x, aA0.x); aA0.y = fmaf(wa, v.y, aA0.y);
    aA0.z = fmaf(wa, v.z, aA0.z); aA0.w = fmaf(wa, v.w, aA0.w);
    aB0.x = fmaf(wb, v.x, aB0.x); aB0.y = fmaf(wb, v.y, aB0.y);
    aB0.z = fmaf(wb, v.z, aB0.z); aB0.w = fmaf(wb, v.w, aB0.w);
    lA += hasA; lB += hasB;
  }
  f4v aA, aB;
  aA.x = aA0.x + aA1.x; aA.y = aA0.y + aA1.y;
  aA.z = aA0.z + aA1.z; aA.w = aA0.w + aA1.w;
  aB.x = aB0.x + aB1.x; aB.y = aB0.y + aB1.y;
  aB.z = aB0.z + aB1.z; aB.w = aB0.w + aB1.w;
  aA.x += __shfl_xor(aA.x, 32); aA.y += __shfl_xor(aA.y, 32);
  aA.z += __shfl_xor(aA.z, 32); aA.w += __shfl_xor(aA.w, 32);
  aB.x += __shfl_xor(aB.x, 32); aB.y += __shfl_xor(aB.y, 32);
  aB.z += __shfl_xor(aB.z, 32); aB.w += __shfl_xor(aB.w, 32);

  f4v bb = *(const f4v*)(bias + li * 4);
  float dv = half ? dvB : dvA;
  f4v av;
  av.x = half ? aB.x : aA.x; av.y = half ? aB.y : aA.y;
  av.z = half ? aB.z : aA.z; av.w = half ? aB.w : aA.w;
  f4v r;
  r.x = fmaxf(fmaf(dv, av.x, bb.x), 0.f);
  r.y = fmaxf(fmaf(dv, av.y, bb.y), 0.f);
  r.z = fmaxf(fmaf(dv, av.z, bb.z), 0.f);
  r.w = fmaxf(fmaf(dv, av.w, bb.w), 0.f);
  int dsel = half ? dB : d0;

  // score epilogue
  size_t rb = ((size_t)b * N_G + dsel) * NH + li * 4;
  f4v u1 = __builtin_nontemporal_load((const f4v*)(h1 + rb));
  f4v u2 = __builtin_nontemporal_load((const f4v*)(h2 + rb));
  const float* twp = topk_w + li * 12;
  const float* fwp = fcW + li * 12;
  f4v ta = *(const f4v*)(twp + 0), tb2 = *(const f4v*)(twp + 4), tc = *(const f4v*)(twp + 8);
  f4v fa = *(const f4v*)(fwp + 0), fb = *(const f4v*)(fwp + 4), fc = *(const f4v*)(fwp + 8);
  float d1 = u1.x * ta.x + u2.x * ta.y + r.x * ta.z
           + u1.y * ta.w + u2.y * tb2.x + r.y * tb2.y
           + u1.z * tb2.z + u2.z * tb2.w + r.z * tc.x
           + u1.w * tc.y + u2.w * tc.z + r.w * tc.w;
  float d2 = u1.x * fa.x + u2.x * fa.y + r.x * fa.z
           + u1.y * fa.w + u2.y * fb.x + r.y * fb.y
           + u1.z * fb.z + u2.z * fb.w + r.z * fc.x
           + u1.w * fc.y + u2.w * fc.z + r.w * fc.w;
#pragma unroll
  for (int sh = 16; sh > 0; sh >>= 1) {
    d1 += __shfl_down(d1, sh, 32);
    d2 += __shfl_down(d2, sh, 32);
  }
  if (li == 0 && (half == 0 || has1)) {
    int gw = b * N_G + dsel;
    float scv = tanhf(d1 * scal[0]);
    score[gw] = scv;
    d2a[gw] = d2;
    unsigned u = __float_as_uint(scv);
    unsigned k32 = (u & 0x80000000u) ? ~u : (u | 0x80000000u);
    keys[gw] = k32;
    atomicAdd(&hist[b * NBIN + (int)(k32 >> 16)], 1);
  }
}

// ---------------- per-batch suffix sums over 65536 bins ----------------
__global__ __launch_bounds__(1024) void suffix_kernel(const int* __restrict__ hist,
                                                      int* __restrict__ suf) {
  __shared__ int buf[1024];
  int b = blockIdx.x;
  const int* hb = hist + b * NBIN;
  int* sb = suf + b * SUFS;
  int t = threadIdx.x;
  int base = t * 64;
  int s = 0;
  for (int k = 0; k < 64; ++k) s += hb[base + k];
  buf[t] = s;
  __syncthreads();
  for (int off = 1; off < 1024; off <<= 1) {
    int v = (t + off < 1024) ? buf[t + off] : 0;
    __syncthreads();
    buf[t] += v;
    __syncthreads();
  }
  int acc = buf[t] - s;
  if (t == 0) sb[NBIN] = 0;
  for (int k = 63; k >= 0; --k) {
    acc += hb[base + k];
    sb[base + k] = acc;
  }
}

// ---------------- bucket scatter (consumes hist via atomicSub) ----------------
__global__ void scatter_kernel(const unsigned* __restrict__ keys, int* __restrict__ hist,
                               const int* __restrict__ suf, int2* __restrict__ bucket) {
  int b = blockIdx.y;
  int i = blockIdx.x * 256 + threadIdx.x;
  if (i >= N_G) return;
  unsigned k = keys[b * N_G + i];
  int bin = (int)(k >> 16);
  int old = atomicSub(&hist[b * NBIN + bin], 1);
  int pos = suf[b * SUFS + bin + 1] + old - 1;
  bucket[b * N_G + pos] = make_int2((int)k, i);
}

// ---------------- exact stable-descending rank + z scatter ----------------
__global__ void rank_z_kernel(const unsigned* __restrict__ keys, const int* __restrict__ suf,
                              const int2* __restrict__ bucket, const float* __restrict__ score,
                              const float* __restrict__ d2a, const float* __restrict__ fcb,
                              float* __restrict__ z) {
  int b = blockIdx.y;
  int i = blockIdx.x * 256 + threadIdx.x;
  if (i >= N_G) return;
  int gw = b * N_G + i;
  unsigned k = keys[gw];
  int bin = (int)(k >> 16);
  int lo = suf[b * SUFS + bin + 1];
  int hi = suf[b * SUFS + bin];
  int r = lo;
  const int2* bk = bucket + b * N_G;
  for (int p = lo; p < hi; ++p) {
    int2 e = bk[p];
    unsigned kj = (unsigned)e.x;
    r += (kj > k || (kj == k && e.y < i)) ? 1 : 0;
  }
  if (r < K_TOP) z[b * K_TOP + r] = fmaf(score[gw], d2a[gw], fcb[0]);
}

// ---------------- lin1: all 8 batches per block (W read once) ----------------
__global__ __launch_bounds__(256) void lin1_kernel(const float* __restrict__ z,
                                                   const float* __restrict__ W,
                                                   float* __restrict__ hpre) {
  __shared__ float zb[8][237];
  int rs = blockIdx.x;
  int r0 = rs * 237;
  int rn = K_TOP - r0; if (rn > 237) rn = 237;
  for (int t = threadIdx.x; t < 8 * rn; t += 256) {
    int bb = t / rn, rr = t - bb * rn;
    zb[bb][rr] = z[bb * K_TOP + r0 + rr];
  }
  __syncthreads();
  int c = threadIdx.x;
  float a[8][2];
#pragma unroll
  for (int bb = 0; bb < 8; ++bb) { a[bb][0] = 0.f; a[bb][1] = 0.f; }
  for (int r = 0; r < rn; ++r) {
    const float* wr = W + (size_t)(r0 + r) * 512;
    float w0 = wr[c], w1 = wr[c + 256];
#pragma unroll
    for (int bb = 0; bb < 8; ++bb) {
      float zz = zb[bb][r];
      a[bb][0] = fmaf(zz, w0, a[bb][0]);
      a[bb][1] = fmaf(zz, w1, a[bb][1]);
    }
  }
#pragma unroll
  for (int bb = 0; bb < 8; ++bb) {
    atomicAdd(&hpre[bb * 512 + c], a[bb][0]);
    atomicAdd(&hpre[bb * 512 + c + 256], a[bb][1]);
  }
}

// ---------------- lin2 + log_softmax ----------------
__global__ __launch_bounds__(128) void lin2_kernel(const float* __restrict__ hpre,
                                                   const float* __restrict__ l1b,
                                                   const float* __restrict__ W2,
                                                   const float* __restrict__ l2b,
                                                   float* __restrict__ out) {
  int b = blockIdx.x, tid = threadIdx.x;
  float a0 = 0.f, a1 = 0.f;
  for (int j = tid; j < 512; j += 128) {
    float t = fmaxf(hpre[b * 512 + j] + l1b[j], 0.f);
    a0 = fmaf(t, W2[j * 2 + 0], a0);
    a1 = fmaf(t, W2[j * 2 + 1], a1);
  }
#pragma unroll
  for (int s = 32; s > 0; s >>= 1) {
    a0 += __shfl_down(a0, s);
    a1 += __shfl_down(a1, s);
  }
  __shared__ float red[2][2];
  if ((tid & 63) == 0) { red[tid >> 6][0] = a0; red[tid >> 6][1] = a1; }
  __syncthreads();
  if (tid == 0) {
    float l0 = red[0][0] + red[1][0] + l2b[0];
    float l1 = red[0][1] + red[1][1] + l2b[1];
    float m = fmaxf(l0, l1);
    float lse = m + logf(expf(l0 - m) + expf(l1 - m));
    out[b * 2 + 0] = l0 - lse;
    out[b * 2 + 1] = l1 - lse;
  }
}

extern "C" void kernel_launch(void* const* d_in, const int* in_sizes, int n_in,
                              void* d_out, int out_size, void* d_ws, size_t ws_size,
                              hipStream_t stream) {
  const float* x   = (const float*)d_in[0];
  const int*   ei  = (const int*)d_in[2];
  const float* W1  = (const float*)d_in[3];
  const float* b1  = (const float*)d_in[4];
  const float* W2  = (const float*)d_in[5];
  const float* b2  = (const float*)d_in[6];
  const float* W3  = (const float*)d_in[7];
  const float* b3  = (const float*)d_in[8];
  const float* tkw = (const float*)d_in[9];
  const float* fcW = (const float*)d_in[10];
  const float* fcb = (const float*)d_in[11];
  const float* l1W = (const float*)d_in[12];
  const float* l1b = (const float*)d_in[13];
  const float* l2W = (const float*)d_in[14];
  const float* l2b = (const float*)d_in[15];
  float* out = (float*)d_out;

  char* ws = (char*)d_ws;
  size_t off = 0;
  auto alloc = [&](size_t bytes) {
    char* p = ws + off;
    off += (bytes + 255) & ~(size_t)255;
    return p;
  };
  // zero-init region (contiguous): cnt, fillc, gctr, hpre, hist
  int*   cnt   = (int*)alloc(15136 * 4);
  int*   fillc = (int*)alloc(15136 * 4);
  int*   gctr  = (int*)alloc(256);
  float* hpre  = (float*)alloc(4096 * 4);
  int*   hist  = (int*)alloc((size_t)BSZ * NBIN * 4);
  // --- end zero region ---
  int*   rowstart = (int*)alloc(15136 * 4);
  float* dinv  = (float*)alloc(15136 * 4);
  int4*  rowdesc = (int4*)alloc(15136 * 16);
  float* scal  = (float*)alloc(64);
  float* z     = (float*)alloc((size_t)BSZ * K_TOP * 4);
  float* score = (float*)alloc(121088 * 4);
  float* d2a   = (float*)alloc(121088 * 4);
  unsigned* keys = (unsigned*)alloc(121088 * 4);
  int*   suf   = (int*)alloc((size_t)BSZ * SUFS * 4);
  int2*  bucket = (int2*)alloc(121088 * 8);
  int2*  csr   = (int2*)alloc((size_t)E_N * 8);
  float* ax = (float*)alloc((size_t)BSZ * N_G * 64 * 4);
  float* hw = (float*)alloc((size_t)BSZ * N_G * NH * 4);  // fp32 (layer2) / fp16 (layer3, half used)
  float* h1 = (float*)alloc((size_t)BSZ * N_G * NH * 4);
  float* h2 = (float*)alloc((size_t)BSZ * N_G * NH * 4);
  (void)ws_size; (void)in_sizes; (void)n_in; (void)out_size;

  int zero_n = (int)(((char*)rowstart - (char*)cnt) / 4);
  zero_kernel<<<(zero_n + 1023) / 1024, 1024, 0, stream>>>(cnt, zero_n);
  count_kernel<<<(E_N + 255) / 256, 256, 0, stream>>>(ei, cnt);
  scan_kernel<<<(N_G + 1023) / 1024, 1024, 0, stream>>>(cnt, rowstart, dinv, rowdesc, gctr, tkw, scal);
  fill_kernel<<<(E_N + 255) / 256, 256, 0, stream>>>(ei, rowstart, dinv, fillc, csr);

  dim3 mmg(8 * 237);  // batch-pinned: b = blk&7
  int aggblocks2 = 8 * ((N_G + 7) / 8);   // 2 rows/wave agg kernels

  // layer 1: dual-row 8-deep agg(x) @ W1 (commutation)
  agg64x2_kernel<<<aggblocks2, 256, 0, stream>>>(x, csr, rowdesc, ax);
  mm_kernel<64, true, false><<<mmg, 256, 0, stream>>>(ax, W1, b1, h1);
  // layer 2: fp32 full-width agg, 2 edges/gather, 8 VMEM outstanding
  mm_kernel<128, false, false><<<mmg, 256, 0, stream>>>(h1, W2, nullptr, hw);
  agg128_f4_kernel<<<aggblocks2, 256, 0, stream>>>(hw, csr, rowdesc, b2, h2);
  // layer 3: fp16 table (L2-fit), dual-row batch8, fused score
  mm_kernel<128, false, true><<<mmg, 256, 0, stream>>>(h2, W3, nullptr, hw);
  agg128h2_score_kernel<<<aggblocks2, 256, 0, stream>>>((const __half*)hw, csr, rowdesc, b3,
                                                        h1, h2, tkw, fcW, scal,
                                                        score, d2a, keys, hist);

  dim3 ng((N_G + 255) / 256, BSZ);
  suffix_kernel<<<BSZ, 1024, 0, stream>>>(hist, suf);
  scatter_kernel<<<ng, 256, 0, stream>>>(keys, hist, suf, bucket);
  rank_z_kernel<<<ng, 256, 0, stream>>>(keys, suf, bucket, score, d2a, fcb, z);

  lin1_kernel<<<32, 256, 0, stream>>>(z, l1W, hpre);
  lin2_kernel<<<BSZ, 128, 0, stream>>>(hpre, l1b, l2W, l2b, out);
}